// Round 3
// baseline (1333.827 us; speedup 1.0000x reference)
//
#include <hip/hip_runtime.h>
#include <math.h>

#define K_IN 12288
#define HID  1024
#define G4   4096
#define TS   256

typedef unsigned long long u64;
typedef unsigned int u32;
typedef __attribute__((ext_vector_type(8))) short bf16x8;
typedef __attribute__((ext_vector_type(4))) short short4v;
typedef __attribute__((ext_vector_type(4))) float f32x4;

// fp32 -> (bf16 hi, bf16 lo) split. hi = truncation (top 16 bits), lo = bf16
// of the residual (also truncated). Missing lo*lo + trunc error ~2^-17 rel.
__device__ __forceinline__ void cvt_split(const float4 v, short4v& h, short4v& l) {
  u32 b0 = __float_as_uint(v.x), b1 = __float_as_uint(v.y),
      b2 = __float_as_uint(v.z), b3 = __float_as_uint(v.w);
  float h0 = __uint_as_float(b0 & 0xffff0000u);
  float h1 = __uint_as_float(b1 & 0xffff0000u);
  float h2 = __uint_as_float(b2 & 0xffff0000u);
  float h3 = __uint_as_float(b3 & 0xffff0000u);
  float l0 = v.x - h0, l1 = v.y - h1, l2 = v.z - h2, l3 = v.w - h3;
  h = (short4v){(short)(b0 >> 16), (short)(b1 >> 16),
                (short)(b2 >> 16), (short)(b3 >> 16)};
  l = (short4v){(short)(__float_as_uint(l0) >> 16), (short)(__float_as_uint(l1) >> 16),
                (short)(__float_as_uint(l2) >> 16), (short)(__float_as_uint(l3) >> 16)};
}

// ---------------------------------------------------------------------------
// Kernel 1: split-bf16 MFMA GEMM. xpart[ks][t][j] = dot(x[t,kspan], W[j,kspan])
// Tile: j=64 x t=256 (full N -> W read once), K-split over blockIdx.x.
// 3 MFMA passes (hi*hi, hi*lo, lo*hi) on 16x16x32 bf16. Wave w owns t-range
// [w*64, w*64+64), full j=64: acc[4(jt)][4(tt)] f32x4.
// A-frag: lane&15 = j(m), (lane>>4)*8 = k-chunk. B-frag: lane&15 = t(n).
// D: row(m) = (lane>>4)*4 + reg, col(n) = lane&15   [guide §3, m89/m91-verified]
// ---------------------------------------------------------------------------
#define GJ 64
#define GK 32
#define LDB 40   // bf16 row stride (32 + 8 pad)

__global__ __launch_bounds__(256, 1) void xproj_gemm_mfma(
    const float* __restrict__ X,    // (256, 12288)
    const float* __restrict__ W,    // (4096, 12288)
    float* __restrict__ xpart,      // (nks, 256, 4096)
    int kspan)
{
  __shared__ short Ahi[GJ * LDB], Alo[GJ * LDB];     // 5 KB each
  __shared__ short Bhi[TS * LDB], Blo[TS * LDB];     // 20 KB each

  const int tid = threadIdx.x;
  const int ks = blockIdx.x;
  const int j0 = blockIdx.y * GJ;
  const int kbeg = ks * kspan, kend = kbeg + kspan;
  const int lane = tid & 63, wave = tid >> 6;
  const int rowg = tid >> 3;   // 0..31
  const int kc = tid & 7;      // float4 column within 32-k block

  f32x4 acc[4][4];
#pragma unroll
  for (int a = 0; a < 4; ++a)
#pragma unroll
    for (int b = 0; b < 4; ++b) acc[a][b] = (f32x4){0.f, 0.f, 0.f, 0.f};

  float4 ra[2], rb[8];
  // preload first k-block (A: 64 rows x 2 iters, B: 256 rows x 8 iters)
#pragma unroll
  for (int i = 0; i < 2; ++i)
    ra[i] = *(const float4*)(W + (size_t)(j0 + rowg + i * 32) * K_IN + kbeg + kc * 4);
#pragma unroll
  for (int i = 0; i < 8; ++i)
    rb[i] = *(const float4*)(X + (size_t)(rowg + i * 32) * K_IN + kbeg + kc * 4);

  for (int k0 = kbeg; k0 < kend; k0 += GK) {
    __syncthreads();  // previous iteration's LDS readers done
#pragma unroll
    for (int i = 0; i < 2; ++i) {
      short4v h, l; cvt_split(ra[i], h, l);
      *(short4v*)&Ahi[(rowg + i * 32) * LDB + kc * 4] = h;
      *(short4v*)&Alo[(rowg + i * 32) * LDB + kc * 4] = l;
    }
#pragma unroll
    for (int i = 0; i < 8; ++i) {
      short4v h, l; cvt_split(rb[i], h, l);
      *(short4v*)&Bhi[(rowg + i * 32) * LDB + kc * 4] = h;
      *(short4v*)&Blo[(rowg + i * 32) * LDB + kc * 4] = l;
    }
    __syncthreads();  // LDS tiles ready
    if (k0 + GK < kend) {  // prefetch next k-block (waitcnt lands next iter)
#pragma unroll
      for (int i = 0; i < 2; ++i)
        ra[i] = *(const float4*)(W + (size_t)(j0 + rowg + i * 32) * K_IN + k0 + GK + kc * 4);
#pragma unroll
      for (int i = 0; i < 8; ++i)
        rb[i] = *(const float4*)(X + (size_t)(rowg + i * 32) * K_IN + k0 + GK + kc * 4);
    }
    const int m = lane & 15, quad = lane >> 4;
    bf16x8 ah[4], al[4];
#pragma unroll
    for (int jt = 0; jt < 4; ++jt) {
      ah[jt] = *(const bf16x8*)&Ahi[(jt * 16 + m) * LDB + quad * 8];
      al[jt] = *(const bf16x8*)&Alo[(jt * 16 + m) * LDB + quad * 8];
    }
#pragma unroll
    for (int tt = 0; tt < 4; ++tt) {
      const int trow = wave * 64 + tt * 16 + m;
      bf16x8 bh = *(const bf16x8*)&Bhi[trow * LDB + quad * 8];
      bf16x8 bl = *(const bf16x8*)&Blo[trow * LDB + quad * 8];
#pragma unroll
      for (int jt = 0; jt < 4; ++jt) {
        acc[jt][tt] = __builtin_amdgcn_mfma_f32_16x16x32_bf16(ah[jt], bh, acc[jt][tt], 0, 0, 0);
        acc[jt][tt] = __builtin_amdgcn_mfma_f32_16x16x32_bf16(ah[jt], bl, acc[jt][tt], 0, 0, 0);
        acc[jt][tt] = __builtin_amdgcn_mfma_f32_16x16x32_bf16(al[jt], bh, acc[jt][tt], 0, 0, 0);
      }
    }
  }

  float* outp = xpart + (size_t)ks * TS * G4;
  const int m = lane & 15, quad = lane >> 4;
#pragma unroll
  for (int tt = 0; tt < 4; ++tt) {
    const int t = wave * 64 + tt * 16 + m;
#pragma unroll
    for (int jt = 0; jt < 4; ++jt)
      *(f32x4*)(outp + (size_t)t * G4 + j0 + jt * 16 + quad * 4) = acc[jt][tt];
  }
}

// ---------------------------------------------------------------------------
// Kernel 1b: xproj[t][j] = sum_ks xpart[ks][t][j] + b_ih[j] + b_hh[j]
// ---------------------------------------------------------------------------
__global__ __launch_bounds__(256) void xproj_reduce(
    const float* __restrict__ xpart, int nks,
    const float* __restrict__ b_ih, const float* __restrict__ b_hh,
    float* __restrict__ xproj)
{
  const int idx = (blockIdx.x * 256 + threadIdx.x) * 4;
  float4 s = *(const float4*)(xpart + idx);
  for (int ks = 1; ks < nks; ++ks) {
    float4 p = *(const float4*)(xpart + (size_t)ks * TS * G4 + idx);
    s.x += p.x; s.y += p.y; s.z += p.z; s.w += p.w;
  }
  const int j = idx & (G4 - 1);
  float4 bi = *(const float4*)(b_ih + j);
  float4 bh = *(const float4*)(b_hh + j);
  s.x += bi.x + bh.x; s.y += bi.y + bh.y; s.z += bi.z + bh.z; s.w += bi.w + bh.w;
  *(float4*)(xproj + idx) = s;
}

// ---------------------------------------------------------------------------
// Kernel 2: persistent LSTM scan, 128 WGs x 256 thr. WG w owns units
// [w*8, w*8+8). Row map: r = tid>>3, gate = r&3, uu = r>>2 -> all 4 gates of
// a unit live in ONE wave -> gate gather via shuffles, c in producer regs,
// ONE barrier/step. h published as packed {tag:u32, val:f32} 8B relaxed
// agent atomics, double-buffered; polls batched (4 loads in flight).
// Wreg pinned in VGPRs via asm barrier (compiler otherwise sinks the loads
// into the t-loop: R2 showed VGPR_Count=84 -> per-step 128KB L2 re-read).
// ---------------------------------------------------------------------------
#define NWG 128
#define UPW 8

__global__ __launch_bounds__(256, 1) void lstm_scan(
    const float* __restrict__ W_hh,   // (4096, 1024)
    const float* __restrict__ xproj,  // (256, 4096)
    u64* __restrict__ hmsg)           // (2, 1024) packed {tag,val}
{
  const int tid = threadIdx.x;
  const int w = blockIdx.x;
  const int u0 = w * UPW;
  const int r = tid >> 3;          // 0..31
  const int sub = tid & 7;         // 8 lanes per row
  const int gate = r & 3;
  const int uu = r >> 2;           // 0..7
  const int hrow = gate * HID + u0 + uu;
  const int lane = tid & 63;

  __shared__ __align__(16) float h_lds[2][8 * 132];

  float4 Wreg[32];
  const float4* wp = (const float4*)(W_hh + (size_t)hrow * HID + sub * 128);
#pragma unroll
  for (int i = 0; i < 32; ++i) {
    float4 v = wp[i];
    asm volatile("" : "+v"(v.x), "+v"(v.y), "+v"(v.z), "+v"(v.w));  // pin
    Wreg[i] = v;
  }

  float c = 0.f;                         // live only in producer lanes
  const int myunit = tid >> 5;           // 0..7
  const bool producer = ((tid & 31) == 0);

  for (int t = 0; t < TS; ++t) {
    float xp = xproj[(size_t)t * G4 + hrow];  // prefetch, hides behind spin
    float partial = 0.f;
    if (t > 0) {
      const u64* slot = hmsg + (t & 1) * HID + tid * 4;
      u64 m0, m1, m2, m3;
      for (;;) {  // all 4 polls in flight per round
        m0 = __hip_atomic_load(slot + 0, __ATOMIC_RELAXED, __HIP_MEMORY_SCOPE_AGENT);
        m1 = __hip_atomic_load(slot + 1, __ATOMIC_RELAXED, __HIP_MEMORY_SCOPE_AGENT);
        m2 = __hip_atomic_load(slot + 2, __ATOMIC_RELAXED, __HIP_MEMORY_SCOPE_AGENT);
        m3 = __hip_atomic_load(slot + 3, __ATOMIC_RELAXED, __HIP_MEMORY_SCOPE_AGENT);
        if ((u32)(m0 >> 32) == (u32)t && (u32)(m1 >> 32) == (u32)t &&
            (u32)(m2 >> 32) == (u32)t && (u32)(m3 >> 32) == (u32)t) break;
      }
      float* hl = h_lds[t & 1];
      const int st = tid >> 5, off = (tid & 31) * 4;
      hl[st * 132 + off + 0] = __uint_as_float((u32)m0);
      hl[st * 132 + off + 1] = __uint_as_float((u32)m1);
      hl[st * 132 + off + 2] = __uint_as_float((u32)m2);
      hl[st * 132 + off + 3] = __uint_as_float((u32)m3);
      __syncthreads();  // the ONLY barrier per step
      const float4* hp = (const float4*)(h_lds[t & 1] + sub * 132);
#pragma unroll
      for (int i = 0; i < 32; ++i) {
        float4 h4 = hp[i];
        partial += Wreg[i].x * h4.x + Wreg[i].y * h4.y +
                   Wreg[i].z * h4.z + Wreg[i].w * h4.w;
      }
    }
    // butterfly: full row-sum lands in all 8 sub-lanes
    partial += __shfl_xor(partial, 1, 64);
    partial += __shfl_xor(partial, 2, 64);
    partial += __shfl_xor(partial, 4, 64);
    float gsum = partial + xp;
    float act = (gate == 2) ? tanhf(gsum) : 1.f / (1.f + expf(-gsum));
    // gather i,f,g,o for this half-wave's unit (lanes base+{0,8,16,24})
    const int base = lane & 32;
    float iv = __shfl(act, base + 0, 64);
    float fv = __shfl(act, base + 8, 64);
    float gv = __shfl(act, base + 16, 64);
    float ov = __shfl(act, base + 24, 64);
    if (producer) {
      c = fv * c + iv * gv;
      float hnew = ov * tanhf(c);
      u64 msg = ((u64)(u32)(t + 1) << 32) | (u64)__float_as_uint(hnew);
      __hip_atomic_store(&hmsg[((t + 1) & 1) * HID + u0 + myunit], msg,
                         __ATOMIC_RELAXED, __HIP_MEMORY_SCOPE_AGENT);
    }
  }
}

// ---------------------------------------------------------------------------
// Kernel 3: out[j] = dot(fc_w[j,:], h_T) + fc_b[j]. h_T packed in hmsg slot 0.
// ---------------------------------------------------------------------------
__global__ __launch_bounds__(256) void fc_kernel(
    const float* __restrict__ fc_w, const float* __restrict__ fc_b,
    const u64* __restrict__ hmsg, float* __restrict__ out)
{
  __shared__ float h_s[HID];
  const int tid = threadIdx.x;
  for (int k = tid; k < HID; k += 256)
    h_s[k] = __uint_as_float((u32)hmsg[k]);
  __syncthreads();
  const int r = tid >> 2;
  const int sub = tid & 3;
  const int j = blockIdx.x * 64 + r;
  const float4* wrow = (const float4*)(fc_w + (size_t)j * HID + sub * 256);
  const float4* hp = (const float4*)(h_s + sub * 256);
  float s = 0.f;
#pragma unroll
  for (int i = 0; i < 64; ++i) {
    float4 wv = wrow[i];
    float4 hv = hp[i];
    s += wv.x * hv.x + wv.y * hv.y + wv.z * hv.z + wv.w * hv.w;
  }
  s += __shfl_xor(s, 1, 64);
  s += __shfl_xor(s, 2, 64);
  if (sub == 0) out[j] = s + fc_b[j];
}

// ---------------------------------------------------------------------------
extern "C" void kernel_launch(void* const* d_in, const int* in_sizes, int n_in,
                              void* d_out, int out_size, void* d_ws, size_t ws_size,
                              hipStream_t stream) {
  const float* frames = (const float*)d_in[0];
  const float* W_ih   = (const float*)d_in[1];
  const float* W_hh   = (const float*)d_in[2];
  const float* b_ih   = (const float*)d_in[3];
  const float* b_hh   = (const float*)d_in[4];
  const float* fc_w   = (const float*)d_in[5];
  const float* fc_b   = (const float*)d_in[6];
  float* out = (float*)d_out;

  const size_t XPROJ_BYTES = (size_t)TS * G4 * 4;  // 4 MB
  int nks = 1;
  if (ws_size >= XPROJ_BYTES * 5 + (1 << 20)) nks = 4;
  else if (ws_size >= XPROJ_BYTES * 3 + (1 << 20)) nks = 2;

  char* ws = (char*)d_ws;
  float* xproj = (float*)ws;
  float* xpart = (float*)(ws + XPROJ_BYTES);
  u64*   hmsg  = (u64*)(ws + XPROJ_BYTES * (1 + nks));
  // hmsg NOT initialized: 0xAA poison tag never matches a real tag in [1,256].

  const int kspan = K_IN / nks;
  xproj_gemm_mfma<<<dim3(nks, G4 / GJ), 256, 0, stream>>>(frames, W_ih, xpart, kspan);
  xproj_reduce<<<dim3(TS * G4 / 4 / 256), 256, 0, stream>>>(xpart, nks, b_ih, b_hh, xproj);
  lstm_scan<<<dim3(NWG), 256, 0, stream>>>(W_hh, xproj, hmsg);
  fc_kernel<<<dim3(12288 / 64), 256, 0, stream>>>(fc_w, fc_b, hmsg, out);
}